// Round 1
// baseline (172.519 us; speedup 1.0000x reference)
//
#include <hip/hip_runtime.h>
#include <math.h>

// Problem constants
#define BB 32
#define TT 4096
#define DD 512
#define SS 256
#define D2 512            // 2*S == D, convenient
static constexpr float INV_SCALE = 10.0f;   // 1/0.1

// ---------------------------------------------------------------------------
// Kernel 1: h = silu(t_star*W1 + b1); q = h @ W2 + b2     (B x D, tiny)
// grid = B blocks, 512 threads
// ---------------------------------------------------------------------------
__global__ __launch_bounds__(512) void k_q(
    const float* __restrict__ t_star, const float* __restrict__ W1,
    const float* __restrict__ b1, const float* __restrict__ W2,
    const float* __restrict__ b2, float* __restrict__ q) {
  const int b = blockIdx.x;
  const int d = threadIdx.x;
  __shared__ float h[DD];
  float x = t_star[b] * W1[d] + b1[d];
  h[d] = x / (1.0f + expf(-x));           // silu
  __syncthreads();
  float acc = b2[d];
#pragma unroll 8
  for (int k = 0; k < DD; ++k) acc += h[k] * W2[k * DD + d];
  q[b * DD + d] = acc;
}

// ---------------------------------------------------------------------------
// Kernel 2: scores[b,t] = dot(q[b], context[b,t,:]) - |t_star[b]-t_ctx[b,t]|*10
// One wave (64 lanes) per t-row; 64 lanes x 8 floats = 512 = D.
// grid = B*T/4 blocks of 256 threads (4 waves).
// ---------------------------------------------------------------------------
__global__ __launch_bounds__(256) void k_scores(
    const float* __restrict__ ctx, const float* __restrict__ q,
    const float* __restrict__ t_star, const float* __restrict__ t_ctx,
    float* __restrict__ scores) {
  const int wave = threadIdx.x >> 6;
  const int lane = threadIdx.x & 63;
  const int b = blockIdx.x / (TT / 4);
  const int t = (blockIdx.x % (TT / 4)) * 4 + wave;

  const float4* cp = (const float4*)(ctx + ((size_t)b * TT + t) * DD);
  const float4* qp = (const float4*)(q + b * DD);
  float4 c0 = cp[lane * 2 + 0];
  float4 c1 = cp[lane * 2 + 1];
  float4 q0 = qp[lane * 2 + 0];
  float4 q1 = qp[lane * 2 + 1];
  float acc = c0.x * q0.x + c0.y * q0.y + c0.z * q0.z + c0.w * q0.w +
              c1.x * q1.x + c1.y * q1.y + c1.z * q1.z + c1.w * q1.w;
#pragma unroll
  for (int off = 32; off > 0; off >>= 1) acc += __shfl_xor(acc, off);
  if (lane == 0) {
    float tb = -fabsf(t_star[b] - t_ctx[b * TT + t]) * INV_SCALE;
    scores[b * TT + t] = acc + tb;
  }
}

// ---------------------------------------------------------------------------
// Kernel 3: softmax over T in-place on scores. grid = B, block = 1024 (16 waves)
// ---------------------------------------------------------------------------
__global__ __launch_bounds__(1024) void k_softmax(float* __restrict__ scores) {
  const int b = blockIdx.x;
  const int tid = threadIdx.x;
  const int lane = tid & 63;
  const int wid = tid >> 6;
  __shared__ float red[16];
  float* s = scores + (size_t)b * TT;

  // max
  float m = -INFINITY;
  for (int t = tid; t < TT; t += 1024) m = fmaxf(m, s[t]);
#pragma unroll
  for (int off = 32; off > 0; off >>= 1) m = fmaxf(m, __shfl_xor(m, off));
  if (lane == 0) red[wid] = m;
  __syncthreads();
  float gm = red[0];
#pragma unroll
  for (int i = 1; i < 16; ++i) gm = fmaxf(gm, red[i]);
  __syncthreads();

  // exp + sum (store exp back)
  float sum = 0.0f;
  for (int t = tid; t < TT; t += 1024) {
    float e = expf(s[t] - gm);
    s[t] = e;
    sum += e;
  }
#pragma unroll
  for (int off = 32; off > 0; off >>= 1) sum += __shfl_xor(sum, off);
  if (lane == 0) red[wid] = sum;
  __syncthreads();
  float gs = 0.0f;
#pragma unroll
  for (int i = 0; i < 16; ++i) gs += red[i];
  float inv = 1.0f / gs;

  // normalize
  for (int t = tid; t < TT; t += 1024) s[t] *= inv;
}

// ---------------------------------------------------------------------------
// Kernel 4: partial pooled. grid = B*NCHUNK blocks, 512 threads (one per d).
// partial[b,c,d] = sum_{t in chunk c} w[b,t]*ctx[b,t,d]
// ---------------------------------------------------------------------------
__global__ __launch_bounds__(512) void k_pool(
    const float* __restrict__ ctx, const float* __restrict__ w,
    float* __restrict__ partial, int nchunk) {
  const int b = blockIdx.x / nchunk;
  const int c = blockIdx.x % nchunk;
  const int d = threadIdx.x;
  const int tpc = TT / nchunk;            // <= 512
  __shared__ float wsh[512];
  for (int i = threadIdx.x; i < tpc; i += 512) wsh[i] = w[(size_t)b * TT + c * tpc + i];
  __syncthreads();

  const float* cbase = ctx + ((size_t)b * TT + (size_t)c * tpc) * DD + d;
  float acc = 0.0f;
  for (int t = 0; t < tpc; ++t) acc += wsh[t] * cbase[(size_t)t * DD];
  partial[((size_t)b * nchunk + c) * DD + d] = acc;
}

// ---------------------------------------------------------------------------
// Kernel 5: reduce partials, out = pooled @ Wout + bout, split mu/log_sigma.
// grid = B, block 512 (one thread per output col j).
// ---------------------------------------------------------------------------
__global__ __launch_bounds__(512) void k_out(
    const float* __restrict__ partial, const float* __restrict__ Wout,
    const float* __restrict__ bout, float* __restrict__ out, int nchunk) {
  const int b = blockIdx.x;
  const int j = threadIdx.x;
  __shared__ float p[DD];
  float acc = 0.0f;
  for (int c = 0; c < nchunk; ++c) acc += partial[((size_t)b * nchunk + c) * DD + j];
  p[j] = acc;
  __syncthreads();
  float o = bout[j];
#pragma unroll 8
  for (int d = 0; d < DD; ++d) o += p[d] * Wout[d * D2 + j];
  if (j < SS) out[b * SS + j] = o;                       // mu
  else        out[BB * SS + b * SS + (j - SS)] = o;      // log_sigma
}

// ---------------------------------------------------------------------------
extern "C" void kernel_launch(void* const* d_in, const int* in_sizes, int n_in,
                              void* d_out, int out_size, void* d_ws, size_t ws_size,
                              hipStream_t stream) {
  const float* ctx    = (const float*)d_in[0];   // (B,T,D)
  const float* t_star = (const float*)d_in[1];   // (B,)
  const float* t_ctx  = (const float*)d_in[2];   // (B,T,1)
  const float* W1     = (const float*)d_in[3];   // (1,D)
  const float* b1     = (const float*)d_in[4];   // (D,)
  const float* W2     = (const float*)d_in[5];   // (D,D)
  const float* b2     = (const float*)d_in[6];   // (D,)
  const float* Wout   = (const float*)d_in[7];   // (D,2S)
  const float* bout   = (const float*)d_in[8];   // (2S,)
  float* out = (float*)d_out;                    // mu (B*S) then log_sigma (B*S)

  // workspace layout (floats)
  float* ws = (float*)d_ws;
  const size_t qOff = 0;                          // B*D      = 16384
  const size_t sOff = qOff + (size_t)BB * DD;     // B*T      = 131072
  const size_t pOff = sOff + (size_t)BB * TT;     // B*nchunk*D

  // pick nchunk so everything fits in ws
  int nchunk = 64;
  size_t need = (pOff + (size_t)BB * 64 * DD) * sizeof(float);
  if (ws_size < need) nchunk = 8;                 // fallback: ~1.1 MB total

  float* q       = ws + qOff;
  float* scores  = ws + sOff;
  float* partial = ws + pOff;

  k_q<<<BB, DD, 0, stream>>>(t_star, W1, b1, W2, b2, q);
  k_scores<<<BB * TT / 4, 256, 0, stream>>>(ctx, q, t_star, t_ctx, scores);
  k_softmax<<<BB, 1024, 0, stream>>>(scores);
  k_pool<<<BB * nchunk, 512, 0, stream>>>(ctx, scores, partial, nchunk);
  k_out<<<BB, 512, 0, stream>>>(partial, Wout, bout, out, nchunk);
}

// Round 2
// 130.630 us; speedup vs baseline: 1.3207x; 1.3207x over previous
//
#include <hip/hip_runtime.h>
#include <math.h>

// Problem constants
#define BB 32
#define TT 4096
#define DD 512
#define SS 256
#define NC 128            // chunks per batch
#define RR 32             // rows per chunk (RR*NC == TT)
#define PAD 67            // LDS scatter stride (conflict-avoiding)
static constexpr float INV_SCALE = 10.0f;   // 1/0.1

// ---------------------------------------------------------------------------
// Kernel 1: h = silu(t_star*W1 + b1); q = h @ W2 + b2     (B x D, tiny)
// ---------------------------------------------------------------------------
__global__ __launch_bounds__(512) void k_q(
    const float* __restrict__ t_star, const float* __restrict__ W1,
    const float* __restrict__ b1, const float* __restrict__ W2,
    const float* __restrict__ b2, float* __restrict__ q) {
  const int b = blockIdx.x;
  const int d = threadIdx.x;
  __shared__ float h[DD];
  float x = t_star[b] * W1[d] + b1[d];
  h[d] = x / (1.0f + expf(-x));           // silu
  __syncthreads();
  float acc = b2[d];
#pragma unroll 8
  for (int k = 0; k < DD; ++k) acc += h[k] * W2[k * DD + d];
  q[b * DD + d] = acc;
}

// ---------------------------------------------------------------------------
// Kernel 2 (fused): per (b, chunk c of 32 rows):
//   scores -> chunk-local softmax stats (m_c, sum_c) -> weighted pooled partial
// ctx is read EXACTLY ONCE (rows held in registers between phases).
// Block = 512 threads = 8 waves; wave w owns rows w*4..w*4+3.
// Each lane holds 8 consecutive floats (2x float4) of each of its 4 rows.
// ---------------------------------------------------------------------------
__global__ __launch_bounds__(512) void k_fused(
    const float* __restrict__ ctx, const float* __restrict__ q,
    const float* __restrict__ t_star, const float* __restrict__ t_ctx,
    float* __restrict__ part_pool,    // [B*NC*DD]
    float* __restrict__ part_ms) {    // [B*NC*2]  (m_c, sum_c)
  const int b    = blockIdx.x / NC;
  const int c    = blockIdx.x % NC;
  const int wid  = threadIdx.x >> 6;
  const int lane = threadIdx.x & 63;
  const int t0   = c * RR;

  __shared__ float s_sc[RR];                 // chunk scores
  __shared__ float red[8 * 8 * PAD];         // wave-partial pooled, scattered

  const float4* qp = (const float4*)(q + b * DD);
  const float4 q0 = qp[lane * 2 + 0];
  const float4 q1 = qp[lane * 2 + 1];
  const float ts = t_star[b];

  float4 d0[4], d1[4];
#pragma unroll
  for (int r = 0; r < 4; ++r) {
    const int t = t0 + wid * 4 + r;
    const float4* cp = (const float4*)(ctx + ((size_t)b * TT + t) * DD);
    d0[r] = cp[lane * 2 + 0];
    d1[r] = cp[lane * 2 + 1];
    float a = d0[r].x * q0.x + d0[r].y * q0.y + d0[r].z * q0.z + d0[r].w * q0.w +
              d1[r].x * q1.x + d1[r].y * q1.y + d1[r].z * q1.z + d1[r].w * q1.w;
#pragma unroll
    for (int off = 32; off > 0; off >>= 1) a += __shfl_xor(a, off);
    if (lane == 0)
      s_sc[wid * 4 + r] = a - fabsf(ts - t_ctx[b * TT + t]) * INV_SCALE;
  }
  __syncthreads();

  // chunk-local softmax stats (computed redundantly per thread; cheap)
  float m = -INFINITY;
#pragma unroll
  for (int t = 0; t < RR; ++t) m = fmaxf(m, s_sc[t]);
  float ssum = 0.0f;
#pragma unroll
  for (int t = 0; t < RR; ++t) ssum += expf(s_sc[t] - m);
  float e[4];
#pragma unroll
  for (int r = 0; r < 4; ++r) e[r] = expf(s_sc[wid * 4 + r] - m);

  // per-lane weighted partial over this wave's 4 rows (registers only)
  float4 p0 = {0, 0, 0, 0}, p1 = {0, 0, 0, 0};
#pragma unroll
  for (int r = 0; r < 4; ++r) {
    p0.x += e[r] * d0[r].x; p0.y += e[r] * d0[r].y;
    p0.z += e[r] * d0[r].z; p0.w += e[r] * d0[r].w;
    p1.x += e[r] * d1[r].x; p1.y += e[r] * d1[r].y;
    p1.z += e[r] * d1[r].z; p1.w += e[r] * d1[r].w;
  }

  // scatter to LDS (stride-PAD avoids bank conflicts), then cross-wave reduce
  const float pv[8] = {p0.x, p0.y, p0.z, p0.w, p1.x, p1.y, p1.z, p1.w};
#pragma unroll
  for (int j = 0; j < 8; ++j) red[(wid * 8 + j) * PAD + lane] = pv[j];
  __syncthreads();

  // thread tid owns output d = tid:  d = lane_src*8 + j  =>  j=d%8, lane_src=d/8
  const int d = threadIdx.x;
  const int jj = d & 7, lsrc = d >> 3;
  float acc = 0.0f;
#pragma unroll
  for (int w = 0; w < 8; ++w) acc += red[(w * 8 + jj) * PAD + lsrc];
  part_pool[((size_t)b * NC + c) * DD + d] = acc;
  if (threadIdx.x == 0) {
    part_ms[(b * NC + c) * 2 + 0] = m;
    part_ms[(b * NC + c) * 2 + 1] = ssum;
  }
}

// ---------------------------------------------------------------------------
// Kernel 3: combine chunks (exact online-softmax merge) + Wout epilogue.
// grid = B, block = 512 (thread j owns output column j).
// ---------------------------------------------------------------------------
__global__ __launch_bounds__(512) void k_combine(
    const float* __restrict__ part_pool, const float* __restrict__ part_ms,
    const float* __restrict__ Wout, const float* __restrict__ bout,
    float* __restrict__ out) {
  const int b = blockIdx.x;
  const int j = threadIdx.x;
  __shared__ float scl[NC];
  __shared__ float pool[DD];

  // global max over chunks (redundant per thread; 128 cached scalar reads)
  float m = -INFINITY;
  for (int c = 0; c < NC; ++c) m = fmaxf(m, part_ms[(b * NC + c) * 2]);
  float Z = 0.0f;
  for (int c = 0; c < NC; ++c) {
    float s = expf(part_ms[(b * NC + c) * 2] - m);
    Z += s * part_ms[(b * NC + c) * 2 + 1];
  }
  if (j < NC) scl[j] = expf(part_ms[(b * NC + j) * 2] - m);
  __syncthreads();

  float acc = 0.0f;
  for (int c = 0; c < NC; ++c)
    acc += scl[c] * part_pool[((size_t)b * NC + c) * DD + j];
  pool[j] = acc / Z;
  __syncthreads();

  float o = bout[j];
#pragma unroll 8
  for (int d = 0; d < DD; ++d) o += pool[d] * Wout[d * DD + j];
  if (j < SS) out[b * SS + j] = o;                        // mu
  else        out[BB * SS + b * SS + (j - SS)] = o;       // log_sigma
}

// ---------------------------------------------------------------------------
extern "C" void kernel_launch(void* const* d_in, const int* in_sizes, int n_in,
                              void* d_out, int out_size, void* d_ws, size_t ws_size,
                              hipStream_t stream) {
  const float* ctx    = (const float*)d_in[0];   // (B,T,D)
  const float* t_star = (const float*)d_in[1];   // (B,)
  const float* t_ctx  = (const float*)d_in[2];   // (B,T,1)
  const float* W1     = (const float*)d_in[3];   // (1,D)
  const float* b1     = (const float*)d_in[4];   // (D,)
  const float* W2     = (const float*)d_in[5];   // (D,D)
  const float* b2     = (const float*)d_in[6];   // (D,)
  const float* Wout   = (const float*)d_in[7];   // (D,2S)
  const float* bout   = (const float*)d_in[8];   // (2S,)
  float* out = (float*)d_out;

  float* ws = (float*)d_ws;
  float* q         = ws;                                  // B*D
  float* part_pool = q + (size_t)BB * DD;                 // B*NC*D
  float* part_ms   = part_pool + (size_t)BB * NC * DD;    // B*NC*2

  k_q<<<BB, DD, 0, stream>>>(t_star, W1, b1, W2, b2, q);
  k_fused<<<BB * NC, 512, 0, stream>>>(ctx, q, t_star, t_ctx, part_pool, part_ms);
  k_combine<<<BB, 512, 0, stream>>>(part_pool, part_ms, Wout, bout, out);
}

// Round 3
// 103.474 us; speedup vs baseline: 1.6673x; 1.2624x over previous
//
#include <hip/hip_runtime.h>
#include <math.h>

// Problem constants
#define BB 32
#define TT 4096
#define DD 512
#define SS 256
#define NC 128            // chunks per batch
#define RR 32             // rows per chunk (RR*NC == TT)
#define PAD 67            // LDS scatter stride (conflict-avoiding)
static constexpr float INV_SCALE = 10.0f;   // 1/0.1

// ---------------------------------------------------------------------------
// Kernel 1: q = silu(t_star*W1+b1) @ W2 + b2.
// grid = B*8 blocks (b, jg); block 512 = 64 outputs x 8 k-groups.
// ---------------------------------------------------------------------------
__global__ __launch_bounds__(512) void k_q(
    const float* __restrict__ t_star, const float* __restrict__ W1,
    const float* __restrict__ b1, const float* __restrict__ W2,
    const float* __restrict__ b2, float* __restrict__ q) {
  const int b   = blockIdx.x >> 3;
  const int jg  = blockIdx.x & 7;
  const int tid = threadIdx.x;
  const int di  = tid & 63;
  const int kg  = tid >> 6;
  __shared__ float h[DD];
  __shared__ float red[8][64];
  {
    float x = t_star[b] * W1[tid] + b1[tid];
    h[tid] = x / (1.0f + __expf(-x));     // silu
  }
  __syncthreads();
  const float* w = W2 + jg * 64 + di;
  float acc = 0.0f;
#pragma unroll 8
  for (int kk = 0; kk < 64; ++kk) {
    const int k = kg * 64 + kk;
    acc += h[k] * w[(size_t)k * DD];
  }
  red[kg][di] = acc;
  __syncthreads();
  if (tid < 64) {
    float s = 0.0f;
#pragma unroll
    for (int g = 0; g < 8; ++g) s += red[g][tid];
    q[b * DD + jg * 64 + tid] = s + b2[jg * 64 + tid];
  }
}

// ---------------------------------------------------------------------------
// Kernel 2 (fused): per (b, chunk of 32 rows): scores -> chunk softmax stats
// -> weighted pooled partial. ctx read EXACTLY ONCE (rows live in registers).
// Block = 512 = 8 waves; wave w owns rows w*4..w*4+3; lane holds 8 floats/row.
// ---------------------------------------------------------------------------
__global__ __launch_bounds__(512) void k_fused(
    const float* __restrict__ ctx, const float* __restrict__ q,
    const float* __restrict__ t_star, const float* __restrict__ t_ctx,
    float* __restrict__ part_pool,    // [B*NC*DD]
    float* __restrict__ part_ms) {    // [B*NC*2]  (m_c, sum_c)
  const int b    = blockIdx.x / NC;
  const int c    = blockIdx.x % NC;
  const int wid  = threadIdx.x >> 6;
  const int lane = threadIdx.x & 63;
  const int t0   = c * RR;

  __shared__ float s_sc[RR];
  __shared__ float red[8 * 8 * PAD];

  const float4* qp = (const float4*)(q + b * DD);
  const float4 q0 = qp[lane * 2 + 0];
  const float4 q1 = qp[lane * 2 + 1];
  const float ts = t_star[b];

  // issue all 8 row loads first (keep them in flight together)
  float4 d0[4], d1[4];
  const float* cbase = ctx + ((size_t)b * TT + t0 + wid * 4) * DD;
#pragma unroll
  for (int r = 0; r < 4; ++r) {
    const float4* cp = (const float4*)(cbase + (size_t)r * DD);
    d0[r] = cp[lane * 2 + 0];
    d1[r] = cp[lane * 2 + 1];
  }
#pragma unroll
  for (int r = 0; r < 4; ++r) {
    float a = d0[r].x * q0.x + d0[r].y * q0.y + d0[r].z * q0.z + d0[r].w * q0.w +
              d1[r].x * q1.x + d1[r].y * q1.y + d1[r].z * q1.z + d1[r].w * q1.w;
#pragma unroll
    for (int off = 32; off > 0; off >>= 1) a += __shfl_xor(a, off);
    if (lane == 0) {
      const int t = t0 + wid * 4 + r;
      s_sc[wid * 4 + r] = a - fabsf(ts - t_ctx[b * TT + t]) * INV_SCALE;
    }
  }
  __syncthreads();

  // wave-parallel chunk softmax stats (each 32-lane half reduces identically)
  float v = s_sc[lane & 31];
  float m = v;
#pragma unroll
  for (int off = 16; off >= 1; off >>= 1) m = fmaxf(m, __shfl_xor(m, off));
  float ex = __expf(v - m);
  float ssum = ex;
#pragma unroll
  for (int off = 16; off >= 1; off >>= 1) ssum += __shfl_xor(ssum, off);

  float e[4];
#pragma unroll
  for (int r = 0; r < 4; ++r) e[r] = __expf(s_sc[wid * 4 + r] - m);

  // per-lane weighted partial over this wave's 4 rows (registers only)
  float4 p0 = {0, 0, 0, 0}, p1 = {0, 0, 0, 0};
#pragma unroll
  for (int r = 0; r < 4; ++r) {
    p0.x += e[r] * d0[r].x; p0.y += e[r] * d0[r].y;
    p0.z += e[r] * d0[r].z; p0.w += e[r] * d0[r].w;
    p1.x += e[r] * d1[r].x; p1.y += e[r] * d1[r].y;
    p1.z += e[r] * d1[r].z; p1.w += e[r] * d1[r].w;
  }

  // scatter to LDS (stride-PAD), cross-wave reduce, coalesced global write
  const float pv[8] = {p0.x, p0.y, p0.z, p0.w, p1.x, p1.y, p1.z, p1.w};
#pragma unroll
  for (int j = 0; j < 8; ++j) red[(wid * 8 + j) * PAD + lane] = pv[j];
  __syncthreads();

  const int d = threadIdx.x;
  const int jj = d & 7, lsrc = d >> 3;
  float acc = 0.0f;
#pragma unroll
  for (int w = 0; w < 8; ++w) acc += red[(w * 8 + jj) * PAD + lsrc];
  part_pool[((size_t)b * NC + c) * DD + d] = acc;
  if (threadIdx.x == 0) {
    part_ms[(b * NC + c) * 2 + 0] = m;
    part_ms[(b * NC + c) * 2 + 1] = ssum;
  }
}

// ---------------------------------------------------------------------------
// Kernel 3: partial chunk-combine. grid = B*8 (b,g); block 512 (thread = d).
// pool2[b,g,d] = sum_{c in g's 16 chunks} exp(m_c - M) * part_pool[b,c,d]
// ---------------------------------------------------------------------------
__global__ __launch_bounds__(512) void k_red(
    const float* __restrict__ part_pool, const float* __restrict__ part_ms,
    float* __restrict__ pool2) {
  const int b = blockIdx.x >> 3;
  const int g = blockIdx.x & 7;
  const int d = threadIdx.x;
  float M = -INFINITY;
  for (int c = 0; c < NC; ++c) M = fmaxf(M, part_ms[(b * NC + c) * 2]);
  float acc = 0.0f;
#pragma unroll
  for (int i = 0; i < 16; ++i) {
    const int c = g * 16 + i;
    const float scl = __expf(part_ms[(b * NC + c) * 2] - M);
    acc += scl * part_pool[((size_t)b * NC + c) * DD + d];
  }
  pool2[((size_t)b * 8 + g) * DD + d] = acc;
}

// ---------------------------------------------------------------------------
// Kernel 4: final reduce + Wout epilogue. grid = B*4 (b,jg); block 128.
// ---------------------------------------------------------------------------
__global__ __launch_bounds__(128) void k_out(
    const float* __restrict__ pool2, const float* __restrict__ part_ms,
    const float* __restrict__ Wout, const float* __restrict__ bout,
    float* __restrict__ out) {
  const int b   = blockIdx.x >> 2;
  const int jg  = blockIdx.x & 3;
  const int tid = threadIdx.x;
  __shared__ float pool[DD];

  float M = -INFINITY;
  for (int c = 0; c < NC; ++c) M = fmaxf(M, part_ms[(b * NC + c) * 2]);
  float Z = 0.0f;
  for (int c = 0; c < NC; ++c)
    Z += __expf(part_ms[(b * NC + c) * 2] - M) * part_ms[(b * NC + c) * 2 + 1];
  const float invZ = 1.0f / Z;

  for (int d = tid; d < DD; d += 128) {
    float s = 0.0f;
#pragma unroll
    for (int g = 0; g < 8; ++g) s += pool2[((size_t)b * 8 + g) * DD + d];
    pool[d] = s * invZ;
  }
  __syncthreads();

  const int j = jg * 128 + tid;
  float o = bout[j];
#pragma unroll 8
  for (int d = 0; d < DD; ++d) o += pool[d] * Wout[(size_t)d * DD + j];
  if (j < SS) out[b * SS + j] = o;                        // mu
  else        out[BB * SS + b * SS + (j - SS)] = o;       // log_sigma
}

// ---------------------------------------------------------------------------
extern "C" void kernel_launch(void* const* d_in, const int* in_sizes, int n_in,
                              void* d_out, int out_size, void* d_ws, size_t ws_size,
                              hipStream_t stream) {
  const float* ctx    = (const float*)d_in[0];   // (B,T,D)
  const float* t_star = (const float*)d_in[1];   // (B,)
  const float* t_ctx  = (const float*)d_in[2];   // (B,T,1)
  const float* W1     = (const float*)d_in[3];   // (1,D)
  const float* b1     = (const float*)d_in[4];   // (D,)
  const float* W2     = (const float*)d_in[5];   // (D,D)
  const float* b2     = (const float*)d_in[6];   // (D,)
  const float* Wout   = (const float*)d_in[7];   // (D,2S)
  const float* bout   = (const float*)d_in[8];   // (2S,)
  float* out = (float*)d_out;

  float* ws = (float*)d_ws;
  float* q         = ws;                                   // B*D
  float* part_pool = q + (size_t)BB * DD;                  // B*NC*D
  float* part_ms   = part_pool + (size_t)BB * NC * DD;     // B*NC*2
  float* pool2     = part_ms + (size_t)BB * NC * 2;        // B*8*D

  k_q<<<BB * 8, 512, 0, stream>>>(t_star, W1, b1, W2, b2, q);
  k_fused<<<BB * NC, 512, 0, stream>>>(ctx, q, t_star, t_ctx, part_pool, part_ms);
  k_red<<<BB * 8, 512, 0, stream>>>(part_pool, part_ms, pool2);
  k_out<<<BB * 4, 128, 0, stream>>>(pool2, part_ms, Wout, bout, out);
}